// Round 1
// baseline (535.518 us; speedup 1.0000x reference)
//
#include <hip/hip_runtime.h>
#include <math.h>

#define SEQ 12
#define NODES 207
#define NFREQ 7  // SEQ/2+1

// ---------------------------------------------------------------------------
// Kernel 1: build per-node circular-convolution taps g[n][d] from the complex
// weight. rfft(ortho) * w -> irfft(ortho) with imag-of-DC/Nyquist discarded
// reduces to: g[d] = (1/12)(wr0 + 2*sum_{k=1..5}(wr_k cos(2pi k d/12)
//                    + wi_k sin(2pi k d/12)) + (-1)^d wr6)
// ---------------------------------------------------------------------------
__global__ void build_taps(const float* __restrict__ w, float* __restrict__ g) {
    int i = blockIdx.x * blockDim.x + threadIdx.x;
    if (i >= NODES * SEQ) return;
    int n = i / SEQ;
    int d = i - n * SEQ;
    const float* wn = w + n * (NFREQ * 2);  // [7][2] re,im
    float acc = wn[0];  // wr0 (imag of DC bin discarded by irfft)
    const float step = 0.52359877559829887308f;  // 2*pi/12
#pragma unroll
    for (int k = 1; k <= 5; ++k) {
        float ang = step * (float)(k * d);
        acc += 2.0f * (wn[2 * k] * __cosf(ang) + wn[2 * k + 1] * __sinf(ang));
    }
    acc += ((d & 1) ? -1.0f : 1.0f) * wn[12];  // Nyquist: wr6 only
    g[i] = acc * (1.0f / 12.0f);
}

// ---------------------------------------------------------------------------
// Kernel 2: streaming. One thread = one row of 12 floats (48 B, 16B-aligned).
// out[t] = x[t] + sum_d g[d] * x[(t+d)%12], fully unrolled (144 FMA).
// ---------------------------------------------------------------------------
__global__ __launch_bounds__(256) void filter_rows(
    const float* __restrict__ x, const float* __restrict__ g,
    float* __restrict__ out) {
    int row = blockIdx.x * 256 + threadIdx.x;  // grid sized exactly
    int n = row % NODES;

    const float4* xv = (const float4*)x + (size_t)row * 3;
    float4 a = xv[0], b = xv[1], c = xv[2];
    float xs[SEQ] = {a.x, a.y, a.z, a.w, b.x, b.y, b.z, b.w,
                     c.x, c.y, c.z, c.w};

    const float4* gv = (const float4*)(g + n * SEQ);
    float4 ga = gv[0], gb = gv[1], gc = gv[2];
    float gs[SEQ] = {ga.x, ga.y, ga.z, ga.w, gb.x, gb.y, gb.z, gb.w,
                     gc.x, gc.y, gc.z, gc.w};

    float o[SEQ];
#pragma unroll
    for (int t = 0; t < SEQ; ++t) {
        float s = xs[t];
#pragma unroll
        for (int d = 0; d < SEQ; ++d) {
            s = fmaf(gs[d], xs[(t + d) % SEQ], s);
        }
        o[t] = s;
    }

    float4* ov = (float4*)out + (size_t)row * 3;
    ov[0] = make_float4(o[0], o[1], o[2], o[3]);
    ov[1] = make_float4(o[4], o[5], o[6], o[7]);
    ov[2] = make_float4(o[8], o[9], o[10], o[11]);
}

extern "C" void kernel_launch(void* const* d_in, const int* in_sizes, int n_in,
                              void* d_out, int out_size, void* d_ws,
                              size_t ws_size, hipStream_t stream) {
    const float* x = (const float*)d_in[0];
    const float* w = (const float*)d_in[1];
    float* out = (float*)d_out;
    float* g = (float*)d_ws;  // 207*12 floats = 9936 B

    // Build taps (tiny).
    build_taps<<<(NODES * SEQ + 255) / 256, 256, 0, stream>>>(w, g);

    // 1024*32*207 = 6,782,976 rows; /256 = 26496 blocks exactly.
    const int rows = 1024 * 32 * NODES;
    filter_rows<<<rows / 256, 256, 0, stream>>>(x, g, out);
}